// Round 1
// baseline (245.183 us; speedup 1.0000x reference)
//
#include <hip/hip_runtime.h>
#include <math.h>

#define NQ 12
#define DIM 4096          // 2^12
#define RS2 0.70710678118654752f

// ------------------------------------------------------------------
// GEMM: com[m][n] = sum_k x[m][k] * W[n][k] + bias[n]
// M=1024, N=512, K=2048, all fp32 row-major (K contiguous for both).
// Tile 64(M) x 32(N), K-tile 32, 256 threads, 4x2 micro-tile/thread.
// ------------------------------------------------------------------
__global__ __launch_bounds__(256) void gemm_kernel(const float* __restrict__ A,
                                                   const float* __restrict__ W,
                                                   const float* __restrict__ bias,
                                                   float* __restrict__ C) {
    __shared__ float As[64][33];
    __shared__ float Bs[32][33];
    const int tid = threadIdx.x;
    const int m0 = blockIdx.x * 64;
    const int n0 = blockIdx.y * 32;
    const int tm = tid >> 4;   // 0..15
    const int tn = tid & 15;   // 0..15
    float acc[4][2] = {};
    for (int k0 = 0; k0 < 2048; k0 += 32) {
        #pragma unroll
        for (int i = 0; i < 8; ++i) {            // A: 64x32 = 2048 elems
            int idx = tid + i * 256;
            int r = idx >> 5, c = idx & 31;
            As[r][c] = A[(m0 + r) * 2048 + k0 + c];
        }
        #pragma unroll
        for (int i = 0; i < 4; ++i) {            // B: 32x32 = 1024 elems
            int idx = tid + i * 256;
            int r = idx >> 5, c = idx & 31;
            Bs[r][c] = W[(n0 + r) * 2048 + k0 + c];
        }
        __syncthreads();
        #pragma unroll
        for (int kk = 0; kk < 32; ++kk) {
            float a0 = As[tm * 4 + 0][kk];
            float a1 = As[tm * 4 + 1][kk];
            float a2 = As[tm * 4 + 2][kk];
            float a3 = As[tm * 4 + 3][kk];
            float b0 = Bs[tn * 2 + 0][kk];
            float b1 = Bs[tn * 2 + 1][kk];
            acc[0][0] += a0 * b0; acc[0][1] += a0 * b1;
            acc[1][0] += a1 * b0; acc[1][1] += a1 * b1;
            acc[2][0] += a2 * b0; acc[2][1] += a2 * b1;
            acc[3][0] += a3 * b0; acc[3][1] += a3 * b1;
        }
        __syncthreads();
    }
    #pragma unroll
    for (int r = 0; r < 4; ++r)
        #pragma unroll
        for (int c = 0; c < 2; ++c) {
            int m = m0 + tm * 4 + r;
            int n = n0 + tn * 2 + c;
            C[m * 512 + n] = acc[r][c] + bias[n];
        }
}

// ------------------------------------------------------------------
// 12-qubit statevector simulation, one block per batch element.
// Wire w <-> bit (11-w). State in LDS: sr/si (16 KB each).
// ang (8 KB) holds com row (init) then xf row (final), exactly 40960 B
// total -> 4 blocks/CU.
// ------------------------------------------------------------------
__global__ __launch_bounds__(256) void circuit_kernel(const float* __restrict__ com,  // (1024,512)
                                                      const float* __restrict__ xf,   // (1024,2048)
                                                      const float* __restrict__ qp,   // (2,12,3)
                                                      float* __restrict__ out) {
    __shared__ float sr[DIM];
    __shared__ float si[DIM];
    __shared__ float ang[2048];
    const int tid = threadIdx.x;
    const int b = blockIdx.x;

    // stage com row; zero state
    for (int i = tid; i < 512; i += 256) ang[i] = com[b * 512 + i];
    for (int i = tid; i < DIM; i += 256) { sr[i] = 0.0f; si[i] = 0.0f; }
    __syncthreads();

    // FRQI-1 closed form: H on wires1..9 from |0>, then UC-RY(com) on wire0.
    // Nonzero only where wires10,11 (bits1..0) == 0. State stays real.
    const float K9 = 0.044194173824159216f;   // 2^-4.5
    for (int j = tid; j < 512; j += 256) {
        int rj = (int)(__brev((unsigned)j) >> 23);       // rev9
        float s, c;
        sincosf(0.5f * ang[rj], &s, &c);
        sr[j << 2]              = c * K9;                 // wire0 = 0
        sr[(1 << 11) | (j << 2)] = s * K9;                // wire0 = 1
    }
    __syncthreads();

    // 2 StronglyEntanglingLayers
    for (int l = 0; l < 2; ++l) {
        for (int w = 0; w < NQ; ++w) {
            const float phi = qp[(l * NQ + w) * 3 + 0];
            const float th  = qp[(l * NQ + w) * 3 + 1];
            const float om  = qp[(l * NQ + w) * 3 + 2];
            float st_, ct, sa, ca, sb, cb;
            sincosf(0.5f * th, &st_, &ct);
            sincosf(0.5f * (phi + om), &sa, &ca);
            sincosf(0.5f * (phi - om), &sb, &cb);
            // Rot = [[e^{-i a} c, -e^{i b} s], [e^{-i b} s, e^{i a} c]]
            const float m00r =  ct * ca,  m00i = -ct * sa;
            const float m01r = -st_ * cb, m01i = -st_ * sb;
            const float m10r =  st_ * cb, m10i = -st_ * sb;
            const float m11r =  ct * ca,  m11i =  ct * sa;
            const int wb = 11 - w;
            const int stride = 1 << wb;
            #pragma unroll 4
            for (int p = tid; p < 2048; p += 256) {
                int i0 = ((p >> wb) << (wb + 1)) | (p & (stride - 1));
                int i1 = i0 | stride;
                float x0r = sr[i0], x0i = si[i0];
                float x1r = sr[i1], x1i = si[i1];
                sr[i0] = m00r * x0r - m00i * x0i + m01r * x1r - m01i * x1i;
                si[i0] = m00r * x0i + m00i * x0r + m01r * x1i + m01i * x1r;
                sr[i1] = m10r * x0r - m10i * x0i + m11r * x1r - m11i * x1i;
                si[i1] = m10r * x0i + m10i * x0r + m11r * x1i + m11i * x1r;
            }
            __syncthreads();
        }
        const int r = l + 1;   // ranges: l % (N-1) + 1
        for (int w = 0; w < NQ; ++w) {
            const int t = (w + r) % NQ;
            const int cb_ = 11 - w, tb = 11 - t;
            const int blo = cb_ < tb ? cb_ : tb;
            const int bhi = cb_ < tb ? tb : cb_;
            #pragma unroll 4
            for (int p = tid; p < 1024; p += 256) {
                int x = ((p >> blo) << (blo + 1)) | (p & ((1 << blo) - 1));
                x = ((x >> bhi) << (bhi + 1)) | (x & ((1 << bhi) - 1));
                int i0 = x | (1 << cb_);          // control=1, target=0
                int i1 = i0 | (1 << tb);          // control=1, target=1
                float tr = sr[i0]; sr[i0] = sr[i1]; sr[i1] = tr;
                float ti = si[i0]; si[i0] = si[i1]; si[i1] = ti;
            }
            __syncthreads();
        }
    }

    // FRQI-2: H on wires 1..11
    for (int w = 1; w <= 11; ++w) {
        const int wb = 11 - w;
        const int stride = 1 << wb;
        #pragma unroll 4
        for (int p = tid; p < 2048; p += 256) {
            int i0 = ((p >> wb) << (wb + 1)) | (p & (stride - 1));
            int i1 = i0 | stride;
            float x0r = sr[i0], x0i = si[i0];
            float x1r = sr[i1], x1i = si[i1];
            sr[i0] = (x0r + x1r) * RS2; si[i0] = (x0i + x1i) * RS2;
            sr[i1] = (x0r - x1r) * RS2; si[i1] = (x0i - x1i) * RS2;
        }
        __syncthreads();
    }

    // stage xf row (reuse ang; all com reads long done)
    for (int i = tid; i < 2048; i += 256) ang[i] = xf[b * 2048 + i];
    __syncthreads();

    // fused UC-RY(img) on wire0 + Z(0) expectation (p1 - p0)
    float acc = 0.0f;
    #pragma unroll 4
    for (int p = tid; p < 2048; p += 256) {
        int rj = (int)(__brev((unsigned)p) >> 21);       // rev11
        float s, c;
        sincosf(0.5f * ang[rj], &s, &c);
        float x0r = sr[p],        x0i = si[p];
        float x1r = sr[p + 2048], x1i = si[p + 2048];
        float n0r = c * x0r - s * x1r, n0i = c * x0i - s * x1i;
        float n1r = s * x0r + c * x1r, n1i = s * x0i + c * x1i;
        acc += (n1r * n1r + n1i * n1i) - (n0r * n0r + n0i * n0i);
    }
    #pragma unroll
    for (int off = 32; off > 0; off >>= 1) acc += __shfl_down(acc, off, 64);
    __syncthreads();                 // all ang reads done before reuse
    if ((tid & 63) == 0) ang[tid >> 6] = acc;
    __syncthreads();
    if (tid == 0) out[b] = ang[0] + ang[1] + ang[2] + ang[3];
}

extern "C" void kernel_launch(void* const* d_in, const int* in_sizes, int n_in,
                              void* d_out, int out_size, void* d_ws, size_t ws_size,
                              hipStream_t stream) {
    const float* x    = (const float*)d_in[0];   // (1024,2,32,32) -> (1024,2048)
    const float* W    = (const float*)d_in[1];   // (512,2048)
    const float* bias = (const float*)d_in[2];   // (512,)
    const float* qp   = (const float*)d_in[3];   // (2,12,3)
    float* out = (float*)d_out;                  // (1024,)
    float* com = (float*)d_ws;                   // (1024,512) scratch, 2 MB

    dim3 ggrid(1024 / 64, 512 / 32);             // 16 x 16 = 256 blocks
    gemm_kernel<<<ggrid, 256, 0, stream>>>(x, W, bias, com);
    circuit_kernel<<<1024, 256, 0, stream>>>(com, x, qp, out);
}

// Round 2
// 215.692 us; speedup vs baseline: 1.1367x; 1.1367x over previous
//
#include <hip/hip_runtime.h>
#include <math.h>

#define RS2f 0.70710678118654752f

// ==================================================================
// Kernel 1: seed com with bias (d_ws is poisoned 0xAA before each call)
// ==================================================================
__global__ __launch_bounds__(256) void init_com(const float* __restrict__ bias,
                                                float* __restrict__ C) {
    int i = blockIdx.x * 256 + threadIdx.x;     // 512K total
    C[i] = bias[i & 511];
}

// ==================================================================
// Kernel 2: GEMM com += x @ W^T, split-K=4 for occupancy.
// M=1024,N=512,K=2048. Tile 64x32, K-chunk 512, atomicAdd epilogue.
// ==================================================================
__global__ __launch_bounds__(256) void gemm_kernel(const float* __restrict__ A,
                                                   const float* __restrict__ W,
                                                   float* __restrict__ C) {
    __shared__ float As[64][33];
    __shared__ float Bs[32][33];
    const int tid = threadIdx.x;
    const int m0 = blockIdx.x * 64;
    const int n0 = blockIdx.y * 32;
    const int kbase = blockIdx.z * 512;
    const int tm = tid >> 4;
    const int tn = tid & 15;
    float acc[4][2] = {};
    for (int k0 = kbase; k0 < kbase + 512; k0 += 32) {
        #pragma unroll
        for (int i = 0; i < 8; ++i) {
            int idx = tid + i * 256;
            int r = idx >> 5, c = idx & 31;
            As[r][c] = A[(m0 + r) * 2048 + k0 + c];
        }
        #pragma unroll
        for (int i = 0; i < 4; ++i) {
            int idx = tid + i * 256;
            int r = idx >> 5, c = idx & 31;
            Bs[r][c] = W[(n0 + r) * 2048 + k0 + c];
        }
        __syncthreads();
        #pragma unroll
        for (int kk = 0; kk < 32; ++kk) {
            float a0 = As[tm * 4 + 0][kk];
            float a1 = As[tm * 4 + 1][kk];
            float a2 = As[tm * 4 + 2][kk];
            float a3 = As[tm * 4 + 3][kk];
            float b0 = Bs[tn * 2 + 0][kk];
            float b1 = Bs[tn * 2 + 1][kk];
            acc[0][0] += a0 * b0; acc[0][1] += a0 * b1;
            acc[1][0] += a1 * b0; acc[1][1] += a1 * b1;
            acc[2][0] += a2 * b0; acc[2][1] += a2 * b1;
            acc[3][0] += a3 * b0; acc[3][1] += a3 * b1;
        }
        __syncthreads();
    }
    #pragma unroll
    for (int r = 0; r < 4; ++r)
        #pragma unroll
        for (int c = 0; c < 2; ++c) {
            int m = m0 + tm * 4 + r;
            int n = n0 + tn * 2 + c;
            atomicAdd(&C[m * 512 + n], acc[r][c]);
        }
}

// ==================================================================
// Kernel 3: 12-qubit circuit, ONE WAVE per batch element, state fully
// in registers (64 complex amps per lane). Index bit layout:
//   idx = (e5<<11) | (lane<<5) | (e&31)
//   e-bits (register): idx bits {11,4,3,2,1,0} = wires {0,7,8,9,10,11}
//   lane-bits (shuffle): idx bits {10..5}       = wires {1..6}
// Zero __syncthreads in the gate sequence (single wave).
// ==================================================================
struct CMat { float m00r,m00i,m01r,m01i,m10r,m10i,m11r,m11i; };

__device__ __forceinline__ CMat mk_rot(const float* __restrict__ qp, int l, int w) {
    const float* g = qp + (l * 12 + w) * 3;
    float phi = g[0], th = g[1], om = g[2];
    float st, ct, sa, ca, sb, cb;
    sincosf(0.5f * th, &st, &ct);
    sincosf(0.5f * (phi + om), &sa, &ca);
    sincosf(0.5f * (phi - om), &sb, &cb);
    CMat M;
    M.m00r =  ct * ca; M.m00i = -ct * sa;
    M.m01r = -st * cb; M.m01i = -st * sb;
    M.m10r =  st * cb; M.m10i = -st * sb;
    M.m11r =  ct * ca; M.m11i =  ct * sa;
    return M;
}

template<int W> struct WI {
    static constexpr bool local = (W == 0) || (W >= 7);
    static constexpr int  eb    = (W == 0) ? 5 : (11 - W);     // if local
    static constexpr int  lm    = (W >= 1 && W <= 6) ? (1 << (6 - W)) : 0;
};

template<int EB>
__device__ __forceinline__ void rot_local(float vr[64], float vi[64], const CMat& M) {
    #pragma unroll
    for (int e = 0; e < 64; ++e) if (!(e & (1 << EB))) {
        const int e1 = e | (1 << EB);
        float x0r = vr[e],  x0i = vi[e];
        float x1r = vr[e1], x1i = vi[e1];
        vr[e]  = M.m00r*x0r - M.m00i*x0i + M.m01r*x1r - M.m01i*x1i;
        vi[e]  = M.m00r*x0i + M.m00i*x0r + M.m01r*x1i + M.m01i*x1r;
        vr[e1] = M.m10r*x0r - M.m10i*x0i + M.m11r*x1r - M.m11i*x1i;
        vi[e1] = M.m10r*x0i + M.m10i*x0r + M.m11r*x1i + M.m11i*x1r;
    }
}

template<int LM>
__device__ __forceinline__ void rot_lane(float vr[64], float vi[64], int lane, const CMat& M) {
    const bool hi = lane & LM;
    const float Ar = hi ? M.m11r : M.m00r, Ai = hi ? M.m11i : M.m00i;
    const float Br = hi ? M.m10r : M.m01r, Bi = hi ? M.m10i : M.m01i;
    #pragma unroll
    for (int e = 0; e < 64; ++e) {
        float pr = __shfl_xor(vr[e], LM, 64);
        float pi = __shfl_xor(vi[e], LM, 64);
        float orr = vr[e], oi = vi[e];
        vr[e] = Ar*orr - Ai*oi + Br*pr - Bi*pi;
        vi[e] = Ar*oi + Ai*orr + Br*pi + Bi*pr;
    }
}

template<int W>
__device__ __forceinline__ void rot_wire(float vr[64], float vi[64], int lane, const CMat& M) {
    if constexpr (WI<W>::local) rot_local<WI<W>::eb>(vr, vi, M);
    else                        rot_lane<WI<W>::lm>(vr, vi, lane, M);
}

template<int C, int T>
__device__ __forceinline__ void cnot(float vr[64], float vi[64], int lane) {
    if constexpr (WI<C>::local && WI<T>::local) {
        constexpr int cb = 1 << WI<C>::eb, tb = 1 << WI<T>::eb;
        #pragma unroll
        for (int e = 0; e < 64; ++e) if ((e & cb) && !(e & tb)) {
            const int e1 = e | tb;
            float t = vr[e]; vr[e] = vr[e1]; vr[e1] = t;
            t = vi[e]; vi[e] = vi[e1]; vi[e1] = t;
        }
    } else if constexpr (WI<C>::local && !WI<T>::local) {
        constexpr int cb = 1 << WI<C>::eb, tm = WI<T>::lm;
        #pragma unroll
        for (int e = 0; e < 64; ++e) if (e & cb) {
            vr[e] = __shfl_xor(vr[e], tm, 64);
            vi[e] = __shfl_xor(vi[e], tm, 64);
        }
    } else if constexpr (!WI<C>::local && WI<T>::local) {
        constexpr int cm = WI<C>::lm, tb = 1 << WI<T>::eb;
        const bool cc = lane & cm;
        #pragma unroll
        for (int e = 0; e < 64; ++e) if (!(e & tb)) {
            const int e1 = e | tb;
            float a = vr[e], b = vr[e1];
            vr[e] = cc ? b : a; vr[e1] = cc ? a : b;
            a = vi[e]; b = vi[e1];
            vi[e] = cc ? b : a; vi[e1] = cc ? a : b;
        }
    } else {
        constexpr int cm = WI<C>::lm, tm = WI<T>::lm;
        const int src = (lane & cm) ? (lane ^ tm) : lane;
        #pragma unroll
        for (int e = 0; e < 64; ++e) {
            vr[e] = __shfl(vr[e], src, 64);
            vi[e] = __shfl(vi[e], src, 64);
        }
    }
}

template<int W>
__device__ __forceinline__ void h_wire(float vr[64], float vi[64], int lane) {
    if constexpr (WI<W>::local) {
        constexpr int tb = 1 << WI<W>::eb;
        #pragma unroll
        for (int e = 0; e < 64; ++e) if (!(e & tb)) {
            const int e1 = e | tb;
            float x0 = vr[e], x1 = vr[e1];
            vr[e] = (x0 + x1) * RS2f; vr[e1] = (x0 - x1) * RS2f;
            x0 = vi[e]; x1 = vi[e1];
            vi[e] = (x0 + x1) * RS2f; vi[e1] = (x0 - x1) * RS2f;
        }
    } else {
        constexpr int m = WI<W>::lm;
        const float sgn = (lane & m) ? -RS2f : RS2f;
        #pragma unroll
        for (int e = 0; e < 64; ++e) {
            float pr = __shfl_xor(vr[e], m, 64);
            float pi = __shfl_xor(vi[e], m, 64);
            vr[e] = pr * RS2f + vr[e] * sgn;
            vi[e] = pi * RS2f + vi[e] * sgn;
        }
    }
}

__global__ __launch_bounds__(64) void circuit_kernel(const float* __restrict__ com,  // (1024,512)
                                                     const float* __restrict__ xf,   // (1024,2048)
                                                     const float* __restrict__ qp,   // (2,12,3)
                                                     float* __restrict__ out) {
    __shared__ float ang[2048];          // com row (first 512) then xf row
    const int lane = threadIdx.x;        // 0..63, one wave
    const int b = blockIdx.x;

    float vr[64], vi[64];

    // ---- stage com row ----
    {
        const float4* c4 = (const float4*)(com + b * 512);
        #pragma unroll
        for (int i = 0; i < 2; ++i)
            ((float4*)ang)[i * 64 + lane] = c4[i * 64 + lane];
    }
    __syncthreads();

    // ---- FRQI-1 closed form ----
    #pragma unroll
    for (int e = 0; e < 64; ++e) { vr[e] = 0.0f; vi[e] = 0.0f; }
    const float K9 = 0.044194173824159216f;   // 2^-4.5
    #pragma unroll
    for (int m = 0; m < 8; ++m) {             // e bits 4..2 = m, e1=e0=0
        int j = (lane << 3) | m;              // wires 1..9 value, wire1 MSB
        int rj = (int)(__brev((unsigned)j) >> 23);
        float s, c;
        sincosf(0.5f * ang[rj], &s, &c);
        vr[m << 2]        = K9 * c;           // wire0 = 0
        vr[32 | (m << 2)] = K9 * s;           // wire0 = 1
    }

    // ---- 2 StronglyEntanglingLayers (l-loop kept runtime: code size) ----
    #pragma unroll 1
    for (int l = 0; l < 2; ++l) {
        { CMat M = mk_rot(qp, l, 0);  rot_wire<0 >(vr, vi, lane, M); }
        { CMat M = mk_rot(qp, l, 1);  rot_wire<1 >(vr, vi, lane, M); }
        { CMat M = mk_rot(qp, l, 2);  rot_wire<2 >(vr, vi, lane, M); }
        { CMat M = mk_rot(qp, l, 3);  rot_wire<3 >(vr, vi, lane, M); }
        { CMat M = mk_rot(qp, l, 4);  rot_wire<4 >(vr, vi, lane, M); }
        { CMat M = mk_rot(qp, l, 5);  rot_wire<5 >(vr, vi, lane, M); }
        { CMat M = mk_rot(qp, l, 6);  rot_wire<6 >(vr, vi, lane, M); }
        { CMat M = mk_rot(qp, l, 7);  rot_wire<7 >(vr, vi, lane, M); }
        { CMat M = mk_rot(qp, l, 8);  rot_wire<8 >(vr, vi, lane, M); }
        { CMat M = mk_rot(qp, l, 9);  rot_wire<9 >(vr, vi, lane, M); }
        { CMat M = mk_rot(qp, l, 10); rot_wire<10>(vr, vi, lane, M); }
        { CMat M = mk_rot(qp, l, 11); rot_wire<11>(vr, vi, lane, M); }
        if (l == 0) {                 // r = 1
            cnot<0,1>(vr,vi,lane);  cnot<1,2>(vr,vi,lane);  cnot<2,3>(vr,vi,lane);
            cnot<3,4>(vr,vi,lane);  cnot<4,5>(vr,vi,lane);  cnot<5,6>(vr,vi,lane);
            cnot<6,7>(vr,vi,lane);  cnot<7,8>(vr,vi,lane);  cnot<8,9>(vr,vi,lane);
            cnot<9,10>(vr,vi,lane); cnot<10,11>(vr,vi,lane); cnot<11,0>(vr,vi,lane);
        } else {                      // r = 2
            cnot<0,2>(vr,vi,lane);  cnot<1,3>(vr,vi,lane);  cnot<2,4>(vr,vi,lane);
            cnot<3,5>(vr,vi,lane);  cnot<4,6>(vr,vi,lane);  cnot<5,7>(vr,vi,lane);
            cnot<6,8>(vr,vi,lane);  cnot<7,9>(vr,vi,lane);  cnot<8,10>(vr,vi,lane);
            cnot<9,11>(vr,vi,lane); cnot<10,0>(vr,vi,lane); cnot<11,1>(vr,vi,lane);
        }
    }

    // ---- FRQI-2 Hadamards on wires 1..11 ----
    h_wire<1>(vr,vi,lane);  h_wire<2>(vr,vi,lane);  h_wire<3>(vr,vi,lane);
    h_wire<4>(vr,vi,lane);  h_wire<5>(vr,vi,lane);  h_wire<6>(vr,vi,lane);
    h_wire<7>(vr,vi,lane);  h_wire<8>(vr,vi,lane);  h_wire<9>(vr,vi,lane);
    h_wire<10>(vr,vi,lane); h_wire<11>(vr,vi,lane);

    // ---- stage xf row (com reads long done) ----
    __syncthreads();
    {
        const float4* x4 = (const float4*)(xf + b * 2048);
        #pragma unroll
        for (int i = 0; i < 8; ++i)
            ((float4*)ang)[i * 64 + lane] = x4[i * 64 + lane];
    }
    __syncthreads();

    // ---- fused UC-RY(img) on wire0 (e-bit 5) + Z(0) expectation ----
    float acc = 0.0f;
    #pragma unroll
    for (int e = 0; e < 32; ++e) {
        int v = (lane << 5) | e;                      // wires 1..11 value
        int rv = (int)(__brev((unsigned)v) >> 21);
        float s, c;
        sincosf(0.5f * ang[rv], &s, &c);
        float x0r = vr[e],      x0i = vi[e];
        float x1r = vr[e | 32], x1i = vi[e | 32];
        float n0r = c * x0r - s * x1r, n0i = c * x0i - s * x1i;
        float n1r = s * x0r + c * x1r, n1i = s * x0i + c * x1i;
        acc += (n1r * n1r + n1i * n1i) - (n0r * n0r + n0i * n0i);
    }
    #pragma unroll
    for (int off = 32; off > 0; off >>= 1) acc += __shfl_down(acc, off, 64);
    if (lane == 0) out[b] = acc;
}

extern "C" void kernel_launch(void* const* d_in, const int* in_sizes, int n_in,
                              void* d_out, int out_size, void* d_ws, size_t ws_size,
                              hipStream_t stream) {
    const float* x    = (const float*)d_in[0];   // (1024,2048)
    const float* W    = (const float*)d_in[1];   // (512,2048)
    const float* bias = (const float*)d_in[2];   // (512,)
    const float* qp   = (const float*)d_in[3];   // (2,12,3)
    float* out = (float*)d_out;                  // (1024,)
    float* com = (float*)d_ws;                   // (1024,512) scratch

    init_com<<<2048, 256, 0, stream>>>(bias, com);
    dim3 ggrid(16, 16, 4);                        // split-K=4 -> 1024 blocks
    gemm_kernel<<<ggrid, 256, 0, stream>>>(x, W, com);
    circuit_kernel<<<1024, 64, 0, stream>>>(com, x, qp, out);
}